// Round 6
// baseline (298.301 us; speedup 1.0000x reference)
//
#include <hip/hip_runtime.h>

typedef __bf16 bf16_t;
typedef __bf16 bf16x8 __attribute__((ext_vector_type(8)));
typedef __bf16 bf16x4 __attribute__((ext_vector_type(4)));
typedef _Float16 f16x4 __attribute__((ext_vector_type(4)));
typedef float floatx4 __attribute__((ext_vector_type(4)));

#define BB 8
#define SS 1024
#define DD 1024
#define NH 16
#define HDD 64
#define BS (BB * SS)  // 8192
#define NH4 (BS * DD / 4)       // 2097152
#define NW4 (DD * DD / 4)       // 262144 = 1<<18
// SCALE * log2(e) folded into Q projection so attention uses exp2 directly
#define QK_SCALE (0.125f * 1.44269504088896340736f)

#define GLDS(g, l) __builtin_amdgcn_global_load_lds( \
    (const __attribute__((address_space(1))) void*)(g), \
    (__attribute__((address_space(3))) void*)(l), 16, 0, 0)

// One fused conversion kernel: hidden (NH4 float4s) then 4 weights (NW4 each).
__global__ void cvt_all(const float* __restrict__ h,
                        const float* __restrict__ w0, const float* __restrict__ w1,
                        const float* __restrict__ w2, const float* __restrict__ w3,
                        bf16_t* hb, bf16_t* wb0, bf16_t* wb1, bf16_t* wb2,
                        bf16_t* wb3) {
  int i = blockIdx.x * blockDim.x + threadIdx.x;
  const float* src; bf16_t* dst; int idx;
  if (i < NH4) { src = h; dst = hb; idx = i; }
  else {
    int j = i - NH4; int w = j >> 18; idx = j & (NW4 - 1);
    src = (w == 0) ? w0 : (w == 1) ? w1 : (w == 2) ? w2 : w3;
    dst = (w == 0) ? wb0 : (w == 1) ? wb1 : (w == 2) ? wb2 : wb3;
  }
  const float4 v = ((const float4*)src)[idx];
  bf16x4 o;
  o.x = (bf16_t)v.x; o.y = (bf16_t)v.y; o.z = (bf16_t)v.z; o.w = (bf16_t)v.w;
  ((bf16x4*)dst)[idx] = o;
}

// C[row][col] = sum_k A[row][k] * W[col][k] (NT), K = DD = 1024, BK = 32.
// Single-barrier double-buffered K-loop: stage(kt+1) issues right after the
// barrier, so its vmcnt drain overlaps the whole compute(kt) phase.
// LDS rows are 64 B (4 chunks of 16 B); chunk c of row r stored at position
// c ^ ((r>>1)&3) -> ds_read_b128 fragment reads are 2-way per bank (free).
__device__ __forceinline__ void gemm_body(
    bf16_t* As, bf16_t* Bs,   // each [2][128*32]
    const bf16_t* __restrict__ A, const bf16_t* __restrict__ W,
    const float* biasC, const float* biasR,
    bf16_t* outb, _Float16* outh, float* outf, int ldc, float scale,
    int bm, int bn)
{
  const int tid = threadIdx.x;
  const int wave = tid >> 6, lane = tid & 63;
  const int l15 = lane & 15, quad = lane >> 4;
  const int wr = wave >> 1, wc = wave & 1;
  const int srow = lane >> 2;                          // 0..15
  const int schunk = (lane & 3) ^ ((lane >> 3) & 3);   // swizzled source chunk

  // per-lane staging source base (row = wave*32 + j*16 + srow, chunk schunk)
  const bf16_t* Ag = A + (size_t)(bm * 128 + wave * 32 + srow) * DD + schunk * 8;
  const bf16_t* Wg = W + (size_t)(bn * 128 + wave * 32 + srow) * DD + schunk * 8;

  auto stage = [&](int kt, int bufi) {
#pragma unroll
    for (int j = 0; j < 2; j++) {
      GLDS(Ag + (size_t)j * 16 * DD + kt * 32,
           (char*)As + bufi * 8192 + wave * 2048 + j * 1024);
      GLDS(Wg + (size_t)j * 16 * DD + kt * 32,
           (char*)Bs + bufi * 8192 + wave * 2048 + j * 1024);
    }
  };

  floatx4 acc[4][4] = {};
  stage(0, 0);

  for (int kt = 0; kt < 32; ++kt) {
    __syncthreads();                     // drains stage(kt) (issued last iter)
    if (kt < 31) stage(kt + 1, (kt + 1) & 1);
    const int bufi = kt & 1;

    bf16x8 af[4], bfg[4];
#pragma unroll
    for (int i = 0; i < 4; i++)
      af[i] = *(const bf16x8*)((char*)As + bufi * 8192 +
               (wr * 64 + i * 16 + l15) * 64 + (quad ^ ((l15 >> 1) & 3)) * 16);
#pragma unroll
    for (int j = 0; j < 4; j++)
      bfg[j] = *(const bf16x8*)((char*)Bs + bufi * 8192 +
               (wc * 64 + j * 16 + l15) * 64 + (quad ^ ((l15 >> 1) & 3)) * 16);
#pragma unroll
    for (int i = 0; i < 4; i++)
#pragma unroll
      for (int j = 0; j < 4; j++)
        acc[i][j] = __builtin_amdgcn_mfma_f32_16x16x32_bf16(
            af[i], bfg[j], acc[i][j], 0, 0, 0);
  }

  // C/D layout: col = lane&15, row = quad*4 + reg (m89-verified)
  const int row0 = bm * 128 + wr * 64 + quad * 4;
  const int col0 = bn * 128 + wc * 64 + l15;
#pragma unroll
  for (int j = 0; j < 4; j++) {
    const int col = col0 + j * 16;
    const float bc = biasC ? biasC[col] : 0.0f;
#pragma unroll
    for (int i = 0; i < 4; i++) {
#pragma unroll
      for (int r = 0; r < 4; r++) {
        const int row = row0 + i * 16 + r;
        float o = acc[i][j][r] + bc + (biasR ? biasR[row] : 0.0f);
        o *= scale;
        if (outb)      outb[(size_t)row * ldc + col] = (bf16_t)o;
        else if (outh) outh[(size_t)row * ldc + col] = (_Float16)o;
        else           outf[(size_t)row * ldc + col] = o;
      }
    }
  }
}

// Fused Q / K / V^T projections, XCD-swizzled: x&7 picks which eighth of
// hb's rows this XCD touches -- identical set for Q-A, K-A, and V-W, so hb
// is fetched ~once per XCD-L2 instead of 8x.
__global__ __launch_bounds__(256) void gemm_qkv(
    const bf16_t* __restrict__ hb,
    const bf16_t* __restrict__ wq, const bf16_t* __restrict__ wk,
    const bf16_t* __restrict__ wv,
    const float* __restrict__ bq, const float* __restrict__ bk,
    const float* __restrict__ bv,
    bf16_t* Qb, bf16_t* Kb, _Float16* Vth)
{
  __shared__ bf16_t As[2 * 128 * 32];
  __shared__ bf16_t Bs[2 * 128 * 32];
  const int x = blockIdx.x;
  const int low = x & 7;
  const int id = x >> 3;          // 0..191
  if (id < 64) {                  // Q
    const int t = id;
    gemm_body(As, Bs, hb, wq, bq, nullptr, Qb, nullptr, nullptr, DD, QK_SCALE,
              (t >> 3) * 8 + low, t & 7);
  } else if (id < 128) {          // K
    const int t = id - 64;
    gemm_body(As, Bs, hb, wk, bk, nullptr, Kb, nullptr, nullptr, DD, 1.0f,
              (t >> 3) * 8 + low, t & 7);
  } else {                        // V^T [d][b*s] f16 (A=Wv, W=hb, row-bias)
    const int t = id - 128;
    gemm_body(As, Bs, wv, hb, nullptr, bv, nullptr, Vth, nullptr, BS, 1.0f,
              t >> 3, (t & 7) * 8 + low);
  }
}

__global__ __launch_bounds__(256) void gemm_out(
    const bf16_t* __restrict__ Cb, const bf16_t* __restrict__ wo,
    const float* __restrict__ bo, float* out)
{
  __shared__ bf16_t As[2 * 128 * 32];
  __shared__ bf16_t Bs[2 * 128 * 32];
  const int x = blockIdx.x;
  const int low = x & 7, t = x >> 3;
  gemm_body(As, Bs, Cb, wo, bo, nullptr, nullptr, nullptr, out, DD, 1.0f,
            (t >> 3) * 8 + low, t & 7);
}

// Flash attention, causal. Q-tile = 128 rows/block (wave owns 32 q-cols of
// S^T). K & V^T tiles cooperatively staged to LDS via GLDS, double-buffered
// (1 barrier/iter). S^T = MFMA(A=K, B=Q) leaves P in exactly the B-operand
// layout of 16x16x16 f16 MFMA -> PV straight from registers. Both K and V^T
// LDS tiles use the XOR chunk swizzle -> all fragment reads conflict-free.
__global__ __launch_bounds__(256, 3) void attn_kernel(
    const bf16_t* __restrict__ Q, const bf16_t* __restrict__ K,
    const _Float16* __restrict__ Vt, bf16_t* __restrict__ ctx)
{
  __shared__ bf16_t   Ksm[2][64 * 64];   // [key][d-chunk-swizzled], rows 128B
  __shared__ _Float16 Vsm[2][64 * 64];   // [d][key-chunk-swizzled], rows 128B

  const int tid = threadIdx.x;
  const int wave = tid >> 6, lane = tid & 63;
  const int l15 = lane & 15, quad = lane >> 4;
  const int srow = lane >> 3;
  const int schunk = (lane & 7) ^ srow;   // swizzled source chunk

  // 1024 blocks: bh = (x&7) + 8*(x>>6) keeps one (b,h) on one XCD;
  // qg descending for load balance.
  const int x = blockIdx.x;
  const int bh = (x & 7) + 8 * (x >> 6);
  const int qg = 7 - ((x >> 3) & 7);
  const int b = bh >> 4, h = bh & 15;
  const size_t base = (size_t)b * (SS * DD) + h * HDD;
  const _Float16* vbase = Vt + (size_t)h * HDD * BS + (size_t)b * SS;

  // Q B-fragments: B[n=q=l15][k=d=quad*8+j]; wave owns q = wave*32 + qi*16
  bf16x8 qf[2][2];
#pragma unroll
  for (int qi = 0; qi < 2; qi++) {
    const int qrow = qg * 128 + wave * 32 + qi * 16 + l15;
    const bf16_t* qp = Q + base + (size_t)qrow * DD + quad * 8;
    qf[qi][0] = *(const bf16x8*)qp;
    qf[qi][1] = *(const bf16x8*)(qp + 32);
  }

  floatx4 oacc[4][2] = {};  // O^T[d = nb*16 + quad*4 + r][q = wave*32+qi*16+l15]
  float lsum[2] = {0.f, 0.f};

  // --- staging lambdas (wave w handles 16 rows of each tile) ---
  auto stageK = [&](int kt, int buf) {
    const bf16_t* g = K + base +
        (size_t)(kt * 64 + wave * 16 + srow) * DD + schunk * 8;
    char* l = (char*)&Ksm[buf][wave * 16 * 64];
    GLDS(g, l);
    GLDS(g + 8 * DD, l + 1024);
  };
  auto stageV = [&](int kt, int buf) {
    const int d = wave * 16 + srow;
    const _Float16* g = vbase + (size_t)d * BS + kt * 64 + schunk * 8;
    char* l = (char*)&Vsm[buf][wave * 16 * 64];
    GLDS(g, l);
    GLDS(g + (size_t)8 * BS, l + 1024);
  };

  const int last = 2 * qg + 1;
  stageK(0, 0); stageV(0, 0);
  int buf = 0;

  for (int kt = 0; kt <= last; ++kt) {
    __syncthreads();  // staged buf ready (drains GLDS vmcnt)
    if (kt < last) { stageK(kt + 1, buf ^ 1); stageV(kt + 1, buf ^ 1); }

    if (!(kt == last && wave < 2)) {  // waves 0/1: last tile fully masked
      // ---- S^T = K Q^T ----
      floatx4 sa[4][2] = {};
#pragma unroll
      for (int kb = 0; kb < 4; kb++) {
        const char* kp = (const char*)&Ksm[buf][0] + (kb * 16 + l15) * 128;
        const bf16x8 k0 = *(const bf16x8*)(kp + ((quad)     ^ (l15 & 7)) * 16);
        const bf16x8 k1 = *(const bf16x8*)(kp + ((quad + 4) ^ (l15 & 7)) * 16);
#pragma unroll
        for (int qi = 0; qi < 2; qi++) {
          sa[kb][qi] = __builtin_amdgcn_mfma_f32_16x16x32_bf16(k0, qf[qi][0], sa[kb][qi], 0, 0, 0);
          sa[kb][qi] = __builtin_amdgcn_mfma_f32_16x16x32_bf16(k1, qf[qi][1], sa[kb][qi], 0, 0, 0);
        }
      }

      // ---- mask + exp2 + pack to f16 B-fragments ----
      const bool diag = (kt >= 2 * qg);
      f16x4 pf[4][2];
#pragma unroll
      for (int kb = 0; kb < 4; kb++)
#pragma unroll
        for (int qi = 0; qi < 2; qi++) {
          const int q_loc = wave * 32 + qi * 16 + l15;
          const int k_base = (kt - 2 * qg) * 64 + kb * 16 + quad * 4;
#pragma unroll
          for (int r = 0; r < 4; r++) {
            float p = exp2f(sa[kb][qi][r]);
            if (diag && (k_base + r > q_loc)) p = 0.f;
            lsum[qi] += p;
            pf[kb][qi][r] = (_Float16)p;
          }
        }

      // ---- O^T += V^T P ----
#pragma unroll
      for (int nb = 0; nb < 4; nb++)
#pragma unroll
        for (int kb = 0; kb < 4; kb++) {
          const int pos = (kb * 2 + (quad >> 1)) ^ (l15 & 7);
          const f16x4 vfr = *(const f16x4*)((const char*)&Vsm[buf][0] +
              (nb * 16 + l15) * 128 + pos * 16 + (quad & 1) * 8);
#pragma unroll
          for (int qi = 0; qi < 2; qi++)
            oacc[nb][qi] = __builtin_amdgcn_mfma_f32_16x16x16f16(
                vfr, pf[kb][qi], oacc[nb][qi], 0, 0, 0);
        }
    }
    buf ^= 1;
  }

  // ---- denom across the 4 quads, then write ctx[q][d] ----
#pragma unroll
  for (int qi = 0; qi < 2; qi++) {
    lsum[qi] += __shfl_xor(lsum[qi], 16);
    lsum[qi] += __shfl_xor(lsum[qi], 32);
    const float inv = 1.0f / lsum[qi];
    const int qrow = qg * 128 + wave * 32 + qi * 16 + l15;
#pragma unroll
    for (int nb = 0; nb < 4; nb++) {
      bf16x4 o4;
#pragma unroll
      for (int r = 0; r < 4; r++) o4[r] = (bf16_t)(oacc[nb][qi][r] * inv);
      *(bf16x4*)&ctx[base + (size_t)qrow * DD + nb * 16 + quad * 4] = o4;
    }
  }
}

extern "C" void kernel_launch(void* const* d_in, const int* in_sizes, int n_in,
                              void* d_out, int out_size, void* d_ws, size_t ws_size,
                              hipStream_t stream) {
  const float* h  = (const float*)d_in[0];
  // d_in[1] = causal mask: exactly causal -> synthesized in-kernel
  const float* Wq = (const float*)d_in[2];
  const float* bq = (const float*)d_in[3];
  const float* Wk = (const float*)d_in[4];
  const float* bk = (const float*)d_in[5];
  const float* Wv = (const float*)d_in[6];
  const float* bv = (const float*)d_in[7];
  const float* Wo = (const float*)d_in[8];
  const float* bo = (const float*)d_in[9];
  float* out = (float*)d_out;

  char* ws = (char*)d_ws;
  bf16_t*   hb  = (bf16_t*)(ws);                 // 16 MB [B*S][D]
  bf16_t*   wqb = (bf16_t*)(ws + (16u << 20));   //  2 MB each
  bf16_t*   wkb = (bf16_t*)(ws + (18u << 20));
  bf16_t*   wvb = (bf16_t*)(ws + (20u << 20));
  bf16_t*   wob = (bf16_t*)(ws + (22u << 20));
  bf16_t*   Qb  = (bf16_t*)(ws + (24u << 20));   // 16 MB [B*S][D]
  bf16_t*   Kb  = (bf16_t*)(ws + (40u << 20));   // 16 MB [B*S][D]
  _Float16* Vth = (_Float16*)(ws + (56u << 20)); // 16 MB [D][B*S] f16
  bf16_t*   Cb  = hb;  // alias: hb dead after QKV GEMMs (stream-ordered)

  cvt_all<<<(NH4 + 4 * NW4) / 256, 256, 0, stream>>>(
      h, Wq, Wk, Wv, Wo, hb, wqb, wkb, wvb, wob);

  gemm_qkv<<<1536, 256, 0, stream>>>(hb, wqb, wkb, wvb, bq, bk, bv,
                                     Qb, Kb, Vth);

  attn_kernel<<<BB * NH * (SS / 128), 256, 0, stream>>>(Qb, Kb, Vth, Cb);

  gemm_out<<<dim3(BS / 128 * (DD / 128)), 256, 0, stream>>>(Cb, wob, bo, out);
}

// Round 7
// 287.740 us; speedup vs baseline: 1.0367x; 1.0367x over previous
//
#include <hip/hip_runtime.h>

typedef __bf16 bf16_t;
typedef __bf16 bf16x8 __attribute__((ext_vector_type(8)));
typedef __bf16 bf16x4 __attribute__((ext_vector_type(4)));
typedef _Float16 f16x4 __attribute__((ext_vector_type(4)));
typedef float floatx4 __attribute__((ext_vector_type(4)));

#define BB 8
#define SS 1024
#define DD 1024
#define NH 16
#define HDD 64
#define BS (BB * SS)  // 8192
#define NH4 (BS * DD / 4)       // 2097152
#define NW4 (DD * DD / 4)       // 262144 = 1<<18
// SCALE * log2(e) folded into Q projection so attention uses exp2 directly
#define QK_SCALE (0.125f * 1.44269504088896340736f)

#define GLDS(g, l) __builtin_amdgcn_global_load_lds( \
    (const __attribute__((address_space(1))) void*)(g), \
    (__attribute__((address_space(3))) void*)(l), 16, 0, 0)

// Fine-grained pipeline primitives (AITER-style): raw barrier, partial vmcnt.
#define WAITVM(n) asm volatile("s_waitcnt vmcnt(" #n ")" ::: "memory")
#define SBAR()    asm volatile("s_barrier" ::: "memory")

// One fused conversion kernel: hidden (NH4 float4s) then 4 weights (NW4 each).
__global__ void cvt_all(const float* __restrict__ h,
                        const float* __restrict__ w0, const float* __restrict__ w1,
                        const float* __restrict__ w2, const float* __restrict__ w3,
                        bf16_t* hb, bf16_t* wb0, bf16_t* wb1, bf16_t* wb2,
                        bf16_t* wb3) {
  int i = blockIdx.x * blockDim.x + threadIdx.x;
  const float* src; bf16_t* dst; int idx;
  if (i < NH4) { src = h; dst = hb; idx = i; }
  else {
    int j = i - NH4; int w = j >> 18; idx = j & (NW4 - 1);
    src = (w == 0) ? w0 : (w == 1) ? w1 : (w == 2) ? w2 : w3;
    dst = (w == 0) ? wb0 : (w == 1) ? wb1 : (w == 2) ? wb2 : wb3;
  }
  const float4 v = ((const float4*)src)[idx];
  bf16x4 o;
  o.x = (bf16_t)v.x; o.y = (bf16_t)v.y; o.z = (bf16_t)v.z; o.w = (bf16_t)v.w;
  ((bf16x4*)dst)[idx] = o;
}

// C[row][col] = sum_k A[row][k] * W[col][k] (NT), K = DD = 1024, BK = 32.
// Triple-buffered pipeline: wait vmcnt(4) -> stage(kt) done, stage(kt+1) in
// flight; raw s_barrier (no drain); stage(kt+2) after barrier (WAR-safe);
// compute(kt). The awaited stage was issued 2 iterations earlier.
// LDS rows 64 B (4 chunks); chunk c of row r at position c ^ ((r>>1)&3).
__device__ __forceinline__ void gemm_body(
    bf16_t* As, bf16_t* Bs,   // each [3][128*32]
    const bf16_t* __restrict__ A, const bf16_t* __restrict__ W,
    const float* biasC, const float* biasR,
    bf16_t* outb, _Float16* outh, float* outf, int ldc, float scale,
    int bm, int bn)
{
  const int tid = threadIdx.x;
  const int wave = tid >> 6, lane = tid & 63;
  const int l15 = lane & 15, quad = lane >> 4;
  const int wr = wave >> 1, wc = wave & 1;
  const int srow = lane >> 2;                          // 0..15
  const int schunk = (lane & 3) ^ ((lane >> 3) & 3);   // swizzled source chunk

  const bf16_t* Ag = A + (size_t)(bm * 128 + wave * 32 + srow) * DD + schunk * 8;
  const bf16_t* Wg = W + (size_t)(bn * 128 + wave * 32 + srow) * DD + schunk * 8;

  auto stage = [&](int kt) {
    const int bufi = kt % 3;
#pragma unroll
    for (int j = 0; j < 2; j++) {
      GLDS(Ag + (size_t)j * 16 * DD + kt * 32,
           (char*)As + bufi * 8192 + wave * 2048 + j * 1024);
      GLDS(Wg + (size_t)j * 16 * DD + kt * 32,
           (char*)Bs + bufi * 8192 + wave * 2048 + j * 1024);
    }
  };

  floatx4 acc[4][4] = {};
  stage(0);
  stage(1);

  for (int kt = 0; kt < 32; ++kt) {
    if (kt < 31) WAITVM(4); else WAITVM(0);
    SBAR();
    if (kt < 30) stage(kt + 2);
    const int bufi = kt % 3;

    bf16x8 af[4], bfg[4];
#pragma unroll
    for (int i = 0; i < 4; i++)
      af[i] = *(const bf16x8*)((char*)As + bufi * 8192 +
               (wr * 64 + i * 16 + l15) * 64 + (quad ^ ((l15 >> 1) & 3)) * 16);
#pragma unroll
    for (int j = 0; j < 4; j++)
      bfg[j] = *(const bf16x8*)((char*)Bs + bufi * 8192 +
               (wc * 64 + j * 16 + l15) * 64 + (quad ^ ((l15 >> 1) & 3)) * 16);
#pragma unroll
    for (int i = 0; i < 4; i++)
#pragma unroll
      for (int j = 0; j < 4; j++)
        acc[i][j] = __builtin_amdgcn_mfma_f32_16x16x32_bf16(
            af[i], bfg[j], acc[i][j], 0, 0, 0);
  }

  // C/D layout: col = lane&15, row = quad*4 + reg (m89-verified)
  const int row0 = bm * 128 + wr * 64 + quad * 4;
  const int col0 = bn * 128 + wc * 64 + l15;
#pragma unroll
  for (int j = 0; j < 4; j++) {
    const int col = col0 + j * 16;
    const float bc = biasC ? biasC[col] : 0.0f;
#pragma unroll
    for (int i = 0; i < 4; i++) {
#pragma unroll
      for (int r = 0; r < 4; r++) {
        const int row = row0 + i * 16 + r;
        float o = acc[i][j][r] + bc + (biasR ? biasR[row] : 0.0f);
        o *= scale;
        if (outb)      outb[(size_t)row * ldc + col] = (bf16_t)o;
        else if (outh) outh[(size_t)row * ldc + col] = (_Float16)o;
        else           outf[(size_t)row * ldc + col] = o;
      }
    }
  }
}

// Fused Q / K / V^T projections, XCD-swizzled: x&7 picks which eighth of
// hb's rows this XCD touches -- identical set for Q-A, K-A, and V-W, so hb
// is fetched ~once per XCD-L2 instead of 8x.
__global__ __launch_bounds__(256) void gemm_qkv(
    const bf16_t* __restrict__ hb,
    const bf16_t* __restrict__ wq, const bf16_t* __restrict__ wk,
    const bf16_t* __restrict__ wv,
    const float* __restrict__ bq, const float* __restrict__ bk,
    const float* __restrict__ bv,
    bf16_t* Qb, bf16_t* Kb, _Float16* Vth)
{
  __shared__ bf16_t As[3 * 128 * 32];
  __shared__ bf16_t Bs[3 * 128 * 32];
  const int x = blockIdx.x;
  const int low = x & 7;
  const int id = x >> 3;          // 0..191
  if (id < 64) {                  // Q
    const int t = id;
    gemm_body(As, Bs, hb, wq, bq, nullptr, Qb, nullptr, nullptr, DD, QK_SCALE,
              (t >> 3) * 8 + low, t & 7);
  } else if (id < 128) {          // K
    const int t = id - 64;
    gemm_body(As, Bs, hb, wk, bk, nullptr, Kb, nullptr, nullptr, DD, 1.0f,
              (t >> 3) * 8 + low, t & 7);
  } else {                        // V^T [d][b*s] f16 (A=Wv, W=hb, row-bias)
    const int t = id - 128;
    gemm_body(As, Bs, wv, hb, nullptr, bv, nullptr, Vth, nullptr, BS, 1.0f,
              t >> 3, (t & 7) * 8 + low);
  }
}

__global__ __launch_bounds__(256) void gemm_out(
    const bf16_t* __restrict__ Cb, const bf16_t* __restrict__ wo,
    const float* __restrict__ bo, float* out)
{
  __shared__ bf16_t As[3 * 128 * 32];
  __shared__ bf16_t Bs[3 * 128 * 32];
  const int x = blockIdx.x;
  const int low = x & 7, t = x >> 3;
  gemm_body(As, Bs, Cb, wo, bo, nullptr, nullptr, nullptr, out, DD, 1.0f,
            (t >> 3) * 8 + low, t & 7);
}

// Flash attention, causal. Q-tile = 128 rows/block. K & V^T tiles staged via
// GLDS, TRIPLE-buffered with the same raw-barrier vmcnt pipeline. S^T =
// MFMA(A=K, B=Q) leaves P in the B-operand layout of 16x16x16 f16 MFMA ->
// PV straight from registers. XOR chunk swizzle on both tiles.
__global__ __launch_bounds__(256, 3) void attn_kernel(
    const bf16_t* __restrict__ Q, const bf16_t* __restrict__ K,
    const _Float16* __restrict__ Vt, bf16_t* __restrict__ ctx)
{
  __shared__ bf16_t   Ksm[3][64 * 64];   // [key][d-chunk-swizzled], rows 128B
  __shared__ _Float16 Vsm[3][64 * 64];   // [d][key-chunk-swizzled], rows 128B

  const int tid = threadIdx.x;
  const int wave = tid >> 6, lane = tid & 63;
  const int l15 = lane & 15, quad = lane >> 4;
  const int srow = lane >> 3;
  const int schunk = (lane & 7) ^ srow;   // swizzled source chunk

  // 1024 blocks: bh = (x&7) + 8*(x>>6) keeps one (b,h) on one XCD;
  // qg descending for load balance.
  const int x = blockIdx.x;
  const int bh = (x & 7) + 8 * (x >> 6);
  const int qg = 7 - ((x >> 3) & 7);
  const int b = bh >> 4, h = bh & 15;
  const size_t base = (size_t)b * (SS * DD) + h * HDD;
  const _Float16* vbase = Vt + (size_t)h * HDD * BS + (size_t)b * SS;

  // Q B-fragments: B[n=q=l15][k=d=quad*8+j]; wave owns q = wave*32 + qi*16
  bf16x8 qf[2][2];
#pragma unroll
  for (int qi = 0; qi < 2; qi++) {
    const int qrow = qg * 128 + wave * 32 + qi * 16 + l15;
    const bf16_t* qp = Q + base + (size_t)qrow * DD + quad * 8;
    qf[qi][0] = *(const bf16x8*)qp;
    qf[qi][1] = *(const bf16x8*)(qp + 32);
  }

  floatx4 oacc[4][2] = {};  // O^T[d = nb*16 + quad*4 + r][q = wave*32+qi*16+l15]
  float lsum[2] = {0.f, 0.f};

  // --- staging (wave w handles 16 rows of each tile; 4 GLDS total/stage) ---
  auto stage = [&](int kt) {
    const int buf = kt % 3;
    const bf16_t* gk = K + base +
        (size_t)(kt * 64 + wave * 16 + srow) * DD + schunk * 8;
    char* lk = (char*)&Ksm[buf][wave * 16 * 64];
    GLDS(gk, lk);
    GLDS(gk + 8 * DD, lk + 1024);
    const int d = wave * 16 + srow;
    const _Float16* gv = vbase + (size_t)d * BS + kt * 64 + schunk * 8;
    char* lv = (char*)&Vsm[buf][wave * 16 * 64];
    GLDS(gv, lv);
    GLDS(gv + (size_t)8 * BS, lv + 1024);
  };

  const int last = 2 * qg + 1;  // >= 1 always
  stage(0);
  stage(1);

  for (int kt = 0; kt <= last; ++kt) {
    if (kt < last) WAITVM(4); else WAITVM(0);
    SBAR();
    if (kt + 2 <= last) stage(kt + 2);
    const int buf = kt % 3;

    if (!(kt == last && wave < 2)) {  // waves 0/1: last tile fully masked
      // ---- S^T = K Q^T ----
      floatx4 sa[4][2] = {};
#pragma unroll
      for (int kb = 0; kb < 4; kb++) {
        const char* kp = (const char*)&Ksm[buf][0] + (kb * 16 + l15) * 128;
        const bf16x8 k0 = *(const bf16x8*)(kp + ((quad)     ^ (l15 & 7)) * 16);
        const bf16x8 k1 = *(const bf16x8*)(kp + ((quad + 4) ^ (l15 & 7)) * 16);
#pragma unroll
        for (int qi = 0; qi < 2; qi++) {
          sa[kb][qi] = __builtin_amdgcn_mfma_f32_16x16x32_bf16(k0, qf[qi][0], sa[kb][qi], 0, 0, 0);
          sa[kb][qi] = __builtin_amdgcn_mfma_f32_16x16x32_bf16(k1, qf[qi][1], sa[kb][qi], 0, 0, 0);
        }
      }

      // ---- mask + exp2 + pack to f16 B-fragments ----
      const bool diag = (kt >= 2 * qg);
      f16x4 pf[4][2];
#pragma unroll
      for (int kb = 0; kb < 4; kb++)
#pragma unroll
        for (int qi = 0; qi < 2; qi++) {
          const int q_loc = wave * 32 + qi * 16 + l15;
          const int k_base = (kt - 2 * qg) * 64 + kb * 16 + quad * 4;
#pragma unroll
          for (int r = 0; r < 4; r++) {
            float p = exp2f(sa[kb][qi][r]);
            if (diag && (k_base + r > q_loc)) p = 0.f;
            lsum[qi] += p;
            pf[kb][qi][r] = (_Float16)p;
          }
        }

      // ---- O^T += V^T P ----
#pragma unroll
      for (int nb = 0; nb < 4; nb++)
#pragma unroll
        for (int kb = 0; kb < 4; kb++) {
          const int pos = (kb * 2 + (quad >> 1)) ^ (l15 & 7);
          const f16x4 vfr = *(const f16x4*)((const char*)&Vsm[buf][0] +
              (nb * 16 + l15) * 128 + pos * 16 + (quad & 1) * 8);
#pragma unroll
          for (int qi = 0; qi < 2; qi++)
            oacc[nb][qi] = __builtin_amdgcn_mfma_f32_16x16x16f16(
                vfr, pf[kb][qi], oacc[nb][qi], 0, 0, 0);
        }
    }
  }

  // ---- denom across the 4 quads, then write ctx[q][d] ----
#pragma unroll
  for (int qi = 0; qi < 2; qi++) {
    lsum[qi] += __shfl_xor(lsum[qi], 16);
    lsum[qi] += __shfl_xor(lsum[qi], 32);
    const float inv = 1.0f / lsum[qi];
    const int qrow = qg * 128 + wave * 32 + qi * 16 + l15;
#pragma unroll
    for (int nb = 0; nb < 4; nb++) {
      bf16x4 o4;
#pragma unroll
      for (int r = 0; r < 4; r++) o4[r] = (bf16_t)(oacc[nb][qi][r] * inv);
      *(bf16x4*)&ctx[base + (size_t)qrow * DD + nb * 16 + quad * 4] = o4;
    }
  }
}

extern "C" void kernel_launch(void* const* d_in, const int* in_sizes, int n_in,
                              void* d_out, int out_size, void* d_ws, size_t ws_size,
                              hipStream_t stream) {
  const float* h  = (const float*)d_in[0];
  // d_in[1] = causal mask: exactly causal -> synthesized in-kernel
  const float* Wq = (const float*)d_in[2];
  const float* bq = (const float*)d_in[3];
  const float* Wk = (const float*)d_in[4];
  const float* bk = (const float*)d_in[5];
  const float* Wv = (const float*)d_in[6];
  const float* bv = (const float*)d_in[7];
  const float* Wo = (const float*)d_in[8];
  const float* bo = (const float*)d_in[9];
  float* out = (float*)d_out;

  char* ws = (char*)d_ws;
  bf16_t*   hb  = (bf16_t*)(ws);                 // 16 MB [B*S][D]
  bf16_t*   wqb = (bf16_t*)(ws + (16u << 20));   //  2 MB each
  bf16_t*   wkb = (bf16_t*)(ws + (18u << 20));
  bf16_t*   wvb = (bf16_t*)(ws + (20u << 20));
  bf16_t*   wob = (bf16_t*)(ws + (22u << 20));
  bf16_t*   Qb  = (bf16_t*)(ws + (24u << 20));   // 16 MB [B*S][D]
  bf16_t*   Kb  = (bf16_t*)(ws + (40u << 20));   // 16 MB [B*S][D]
  _Float16* Vth = (_Float16*)(ws + (56u << 20)); // 16 MB [D][B*S] f16
  bf16_t*   Cb  = hb;  // alias: hb dead after QKV GEMMs (stream-ordered)

  cvt_all<<<(NH4 + 4 * NW4) / 256, 256, 0, stream>>>(
      h, Wq, Wk, Wv, Wo, hb, wqb, wkb, wvb, wob);

  gemm_qkv<<<1536, 256, 0, stream>>>(hb, wqb, wkb, wvb, bq, bk, bv,
                                     Qb, Kb, Vth);

  attn_kernel<<<BB * NH * (SS / 128), 256, 0, stream>>>(Qb, Kb, Vth, Cb);

  gemm_out<<<dim3(BS / 128 * (DD / 128)), 256, 0, stream>>>(Cb, wob, bo, out);
}

// Round 8
// 276.411 us; speedup vs baseline: 1.0792x; 1.0410x over previous
//
#include <hip/hip_runtime.h>

typedef __bf16 bf16_t;
typedef __bf16 bf16x8 __attribute__((ext_vector_type(8)));
typedef __bf16 bf16x4 __attribute__((ext_vector_type(4)));
typedef _Float16 f16x4 __attribute__((ext_vector_type(4)));
typedef float floatx4 __attribute__((ext_vector_type(4)));
typedef float floatx16 __attribute__((ext_vector_type(16)));

#define BB 8
#define SS 1024
#define DD 1024
#define NH 16
#define HDD 64
#define BS (BB * SS)  // 8192
#define NH4 (BS * DD / 4)       // 2097152
#define NW4 (DD * DD / 4)       // 262144 = 1<<18
// SCALE * log2(e) folded into Q projection so attention uses exp2 directly
#define QK_SCALE (0.125f * 1.44269504088896340736f)

#define GLDS(g, l) __builtin_amdgcn_global_load_lds( \
    (const __attribute__((address_space(1))) void*)(g), \
    (__attribute__((address_space(3))) void*)(l), 16, 0, 0)

// One fused conversion kernel: hidden (NH4 float4s) then 4 weights (NW4 each).
__global__ void cvt_all(const float* __restrict__ h,
                        const float* __restrict__ w0, const float* __restrict__ w1,
                        const float* __restrict__ w2, const float* __restrict__ w3,
                        bf16_t* hb, bf16_t* wb0, bf16_t* wb1, bf16_t* wb2,
                        bf16_t* wb3) {
  int i = blockIdx.x * blockDim.x + threadIdx.x;
  const float* src; bf16_t* dst; int idx;
  if (i < NH4) { src = h; dst = hb; idx = i; }
  else {
    int j = i - NH4; int w = j >> 18; idx = j & (NW4 - 1);
    src = (w == 0) ? w0 : (w == 1) ? w1 : (w == 2) ? w2 : w3;
    dst = (w == 0) ? wb0 : (w == 1) ? wb1 : (w == 2) ? wb2 : wb3;
  }
  const float4 v = ((const float4*)src)[idx];
  bf16x4 o;
  o.x = (bf16_t)v.x; o.y = (bf16_t)v.y; o.z = (bf16_t)v.z; o.w = (bf16_t)v.w;
  ((bf16x4*)dst)[idx] = o;
}

// C[row][col] = sum_k A[row][k] * W[col][k] (NT), K = DD = 1024, BK = 64.
// r5 structure (2-barrier, single-buffer, XOR chunk swizzle) + 32x32x16 MFMA:
// wave computes 64x64 via 2x2 tiles of 32x32; A/B frag m|n=lane&31,
// k=(lane>>5)*8+j; C/D col=lane&31, row=(reg&3)+8*(reg>>2)+4*(lane>>5)
// (m74/m101-verified).
__device__ __forceinline__ void gemm_body(
    bf16_t* As, bf16_t* Bs,   // each [128*64]
    const bf16_t* __restrict__ A, const bf16_t* __restrict__ W,
    const float* biasC, const float* biasR,
    bf16_t* outb, _Float16* outh, float* outf, int ldc, float scale,
    int bm, int bn)
{
  const int tid = threadIdx.x;
  const int wave = tid >> 6, lane = tid & 63;
  const int l31 = lane & 31, hi = lane >> 5;
  const int wr = wave >> 1, wc = wave & 1;
  const int srow = lane >> 3;                 // 0..7
  const int schunk = (lane & 7) ^ srow;       // swizzled source chunk

  const bf16_t* Ab = A + (size_t)bm * 128 * DD + schunk * 8;
  const bf16_t* Wb = W + (size_t)bn * 128 * DD + schunk * 8;

  floatx16 acc[2][2] = {};

  for (int kt = 0; kt < DD / 64; ++kt) {
    // stage 128x64 for A and B: wave w rows [w*32, +32), 4 GLDS each matrix
#pragma unroll
    for (int j = 0; j < 4; j++) {
      const int row = wave * 32 + j * 8 + srow;
      GLDS(Ab + (size_t)row * DD + kt * 64,
           (char*)As + wave * 4096 + j * 1024);
      GLDS(Wb + (size_t)row * DD + kt * 64,
           (char*)Bs + wave * 4096 + j * 1024);
    }
    __syncthreads();

#pragma unroll
    for (int s = 0; s < 4; s++) {  // k-step of 16
      const int pos = ((s * 2 + hi) ^ (l31 & 7)) * 16;
      bf16x8 a0 = *(const bf16x8*)((char*)As + (wr * 64 + l31) * 128 + pos);
      bf16x8 a1 = *(const bf16x8*)((char*)As + (wr * 64 + 32 + l31) * 128 + pos);
      bf16x8 b0 = *(const bf16x8*)((char*)Bs + (wc * 64 + l31) * 128 + pos);
      bf16x8 b1 = *(const bf16x8*)((char*)Bs + (wc * 64 + 32 + l31) * 128 + pos);
      acc[0][0] = __builtin_amdgcn_mfma_f32_32x32x16_bf16(a0, b0, acc[0][0], 0, 0, 0);
      acc[0][1] = __builtin_amdgcn_mfma_f32_32x32x16_bf16(a0, b1, acc[0][1], 0, 0, 0);
      acc[1][0] = __builtin_amdgcn_mfma_f32_32x32x16_bf16(a1, b0, acc[1][0], 0, 0, 0);
      acc[1][1] = __builtin_amdgcn_mfma_f32_32x32x16_bf16(a1, b1, acc[1][1], 0, 0, 0);
    }
    __syncthreads();
  }

  // epilogue: 32x32 C/D layout (m74/m101)
#pragma unroll
  for (int j = 0; j < 2; j++) {
    const int col = bn * 128 + wc * 64 + j * 32 + l31;
    const float bc = biasC ? biasC[col] : 0.0f;
#pragma unroll
    for (int i = 0; i < 2; i++) {
#pragma unroll
      for (int reg = 0; reg < 16; reg++) {
        const int row = bm * 128 + wr * 64 + i * 32 +
                        (reg & 3) + 8 * (reg >> 2) + 4 * hi;
        float o = acc[i][j][reg] + bc + (biasR ? biasR[row] : 0.0f);
        o *= scale;
        if (outb)      outb[(size_t)row * ldc + col] = (bf16_t)o;
        else if (outh) outh[(size_t)row * ldc + col] = (_Float16)o;
        else           outf[(size_t)row * ldc + col] = o;
      }
    }
  }
}

// Fused Q / K / V^T projections, XCD-swizzled: x&7 picks which eighth of
// hb's rows this XCD touches -- identical set for Q-A, K-A, and V-W, so hb
// is fetched ~once per XCD-L2 instead of 8x.
__global__ __launch_bounds__(256) void gemm_qkv(
    const bf16_t* __restrict__ hb,
    const bf16_t* __restrict__ wq, const bf16_t* __restrict__ wk,
    const bf16_t* __restrict__ wv,
    const float* __restrict__ bq, const float* __restrict__ bk,
    const float* __restrict__ bv,
    bf16_t* Qb, bf16_t* Kb, _Float16* Vth)
{
  __shared__ bf16_t As[128 * 64];
  __shared__ bf16_t Bs[128 * 64];
  const int x = blockIdx.x;
  const int low = x & 7;
  const int id = x >> 3;          // 0..191
  if (id < 64) {                  // Q
    const int t = id;
    gemm_body(As, Bs, hb, wq, bq, nullptr, Qb, nullptr, nullptr, DD, QK_SCALE,
              (t >> 3) * 8 + low, t & 7);
  } else if (id < 128) {          // K
    const int t = id - 64;
    gemm_body(As, Bs, hb, wk, bk, nullptr, Kb, nullptr, nullptr, DD, 1.0f,
              (t >> 3) * 8 + low, t & 7);
  } else {                        // V^T [d][b*s] f16 (A=Wv, W=hb, row-bias)
    const int t = id - 128;
    gemm_body(As, Bs, wv, hb, nullptr, bv, nullptr, Vth, nullptr, BS, 1.0f,
              t >> 3, (t & 7) * 8 + low);
  }
}

__global__ __launch_bounds__(256) void gemm_out(
    const bf16_t* __restrict__ Cb, const bf16_t* __restrict__ wo,
    const float* __restrict__ bo, float* out)
{
  __shared__ bf16_t As[128 * 64];
  __shared__ bf16_t Bs[128 * 64];
  const int x = blockIdx.x;
  const int low = x & 7, t = x >> 3;
  gemm_body(As, Bs, Cb, wo, bo, nullptr, nullptr, nullptr, out, DD, 1.0f,
            (t >> 3) * 8 + low, t & 7);
}

// Flash attention, causal (r5 structure). Q-tile = 128 rows/block. K & V^T
// tiles staged via GLDS, double-buffered (1 barrier/iter). S^T = MFMA(A=K,
// B=Q) leaves P in the B-operand layout of 16x16x16 f16 MFMA -> PV straight
// from registers. XOR chunk swizzle on both tiles -> conflict-free.
__global__ __launch_bounds__(256, 3) void attn_kernel(
    const bf16_t* __restrict__ Q, const bf16_t* __restrict__ K,
    const _Float16* __restrict__ Vt, bf16_t* __restrict__ ctx)
{
  __shared__ bf16_t   Ksm[2][64 * 64];   // [key][d-chunk-swizzled], rows 128B
  __shared__ _Float16 Vsm[2][64 * 64];   // [d][key-chunk-swizzled], rows 128B

  const int tid = threadIdx.x;
  const int wave = tid >> 6, lane = tid & 63;
  const int l15 = lane & 15, quad = lane >> 4;
  const int srow = lane >> 3;
  const int schunk = (lane & 7) ^ srow;   // swizzled source chunk

  // 1024 blocks: bh = (x&7) + 8*(x>>6) keeps one (b,h) on one XCD;
  // qg descending for load balance.
  const int x = blockIdx.x;
  const int bh = (x & 7) + 8 * (x >> 6);
  const int qg = 7 - ((x >> 3) & 7);
  const int b = bh >> 4, h = bh & 15;
  const size_t base = (size_t)b * (SS * DD) + h * HDD;
  const _Float16* vbase = Vt + (size_t)h * HDD * BS + (size_t)b * SS;

  // Q B-fragments: B[n=q=l15][k=d=quad*8+j]; wave owns q = wave*32 + qi*16
  bf16x8 qf[2][2];
#pragma unroll
  for (int qi = 0; qi < 2; qi++) {
    const int qrow = qg * 128 + wave * 32 + qi * 16 + l15;
    const bf16_t* qp = Q + base + (size_t)qrow * DD + quad * 8;
    qf[qi][0] = *(const bf16x8*)qp;
    qf[qi][1] = *(const bf16x8*)(qp + 32);
  }

  floatx4 oacc[4][2] = {};  // O^T[d = nb*16 + quad*4 + r][q = wave*32+qi*16+l15]
  float lsum[2] = {0.f, 0.f};

  // --- staging lambdas (wave w handles 16 rows of each tile) ---
  auto stageK = [&](int kt, int buf) {
    const bf16_t* g = K + base +
        (size_t)(kt * 64 + wave * 16 + srow) * DD + schunk * 8;
    char* l = (char*)&Ksm[buf][wave * 16 * 64];
    GLDS(g, l);
    GLDS(g + 8 * DD, l + 1024);
  };
  auto stageV = [&](int kt, int buf) {
    const int d = wave * 16 + srow;
    const _Float16* g = vbase + (size_t)d * BS + kt * 64 + schunk * 8;
    char* l = (char*)&Vsm[buf][wave * 16 * 64];
    GLDS(g, l);
    GLDS(g + (size_t)8 * BS, l + 1024);
  };

  const int last = 2 * qg + 1;
  stageK(0, 0); stageV(0, 0);
  int buf = 0;

  for (int kt = 0; kt <= last; ++kt) {
    __syncthreads();  // staged buf ready (drains GLDS vmcnt)
    if (kt < last) { stageK(kt + 1, buf ^ 1); stageV(kt + 1, buf ^ 1); }

    if (!(kt == last && wave < 2)) {  // waves 0/1: last tile fully masked
      // ---- S^T = K Q^T ----
      floatx4 sa[4][2] = {};
#pragma unroll
      for (int kb = 0; kb < 4; kb++) {
        const char* kp = (const char*)&Ksm[buf][0] + (kb * 16 + l15) * 128;
        const bf16x8 k0 = *(const bf16x8*)(kp + ((quad)     ^ (l15 & 7)) * 16);
        const bf16x8 k1 = *(const bf16x8*)(kp + ((quad + 4) ^ (l15 & 7)) * 16);
#pragma unroll
        for (int qi = 0; qi < 2; qi++) {
          sa[kb][qi] = __builtin_amdgcn_mfma_f32_16x16x32_bf16(k0, qf[qi][0], sa[kb][qi], 0, 0, 0);
          sa[kb][qi] = __builtin_amdgcn_mfma_f32_16x16x32_bf16(k1, qf[qi][1], sa[kb][qi], 0, 0, 0);
        }
      }

      // ---- mask + exp2 + pack to f16 B-fragments ----
      const bool diag = (kt >= 2 * qg);
      f16x4 pf[4][2];
#pragma unroll
      for (int kb = 0; kb < 4; kb++)
#pragma unroll
        for (int qi = 0; qi < 2; qi++) {
          const int q_loc = wave * 32 + qi * 16 + l15;
          const int k_base = (kt - 2 * qg) * 64 + kb * 16 + quad * 4;
#pragma unroll
          for (int r = 0; r < 4; r++) {
            float p = exp2f(sa[kb][qi][r]);
            if (diag && (k_base + r > q_loc)) p = 0.f;
            lsum[qi] += p;
            pf[kb][qi][r] = (_Float16)p;
          }
        }

      // ---- O^T += V^T P ----
#pragma unroll
      for (int nb = 0; nb < 4; nb++)
#pragma unroll
        for (int kb = 0; kb < 4; kb++) {
          const int pos = (kb * 2 + (quad >> 1)) ^ (l15 & 7);
          const f16x4 vfr = *(const f16x4*)((const char*)&Vsm[buf][0] +
              (nb * 16 + l15) * 128 + pos * 16 + (quad & 1) * 8);
#pragma unroll
          for (int qi = 0; qi < 2; qi++)
            oacc[nb][qi] = __builtin_amdgcn_mfma_f32_16x16x16f16(
                vfr, pf[kb][qi], oacc[nb][qi], 0, 0, 0);
        }
    }
    buf ^= 1;
  }

  // ---- denom across the 4 quads, then write ctx[q][d] ----
#pragma unroll
  for (int qi = 0; qi < 2; qi++) {
    lsum[qi] += __shfl_xor(lsum[qi], 16);
    lsum[qi] += __shfl_xor(lsum[qi], 32);
    const float inv = 1.0f / lsum[qi];
    const int qrow = qg * 128 + wave * 32 + qi * 16 + l15;
#pragma unroll
    for (int nb = 0; nb < 4; nb++) {
      bf16x4 o4;
#pragma unroll
      for (int r = 0; r < 4; r++) o4[r] = (bf16_t)(oacc[nb][qi][r] * inv);
      *(bf16x4*)&ctx[base + (size_t)qrow * DD + nb * 16 + quad * 4] = o4;
    }
  }
}

extern "C" void kernel_launch(void* const* d_in, const int* in_sizes, int n_in,
                              void* d_out, int out_size, void* d_ws, size_t ws_size,
                              hipStream_t stream) {
  const float* h  = (const float*)d_in[0];
  // d_in[1] = causal mask: exactly causal -> synthesized in-kernel
  const float* Wq = (const float*)d_in[2];
  const float* bq = (const float*)d_in[3];
  const float* Wk = (const float*)d_in[4];
  const float* bk = (const float*)d_in[5];
  const float* Wv = (const float*)d_in[6];
  const float* bv = (const float*)d_in[7];
  const float* Wo = (const float*)d_in[8];
  const float* bo = (const float*)d_in[9];
  float* out = (float*)d_out;

  char* ws = (char*)d_ws;
  bf16_t*   hb  = (bf16_t*)(ws);                 // 16 MB [B*S][D]
  bf16_t*   wqb = (bf16_t*)(ws + (16u << 20));   //  2 MB each
  bf16_t*   wkb = (bf16_t*)(ws + (18u << 20));
  bf16_t*   wvb = (bf16_t*)(ws + (20u << 20));
  bf16_t*   wob = (bf16_t*)(ws + (22u << 20));
  bf16_t*   Qb  = (bf16_t*)(ws + (24u << 20));   // 16 MB [B*S][D]
  bf16_t*   Kb  = (bf16_t*)(ws + (40u << 20));   // 16 MB [B*S][D]
  _Float16* Vth = (_Float16*)(ws + (56u << 20)); // 16 MB [D][B*S] f16
  bf16_t*   Cb  = hb;  // alias: hb dead after QKV GEMMs (stream-ordered)

  cvt_all<<<(NH4 + 4 * NW4) / 256, 256, 0, stream>>>(
      h, Wq, Wk, Wv, Wo, hb, wqb, wkb, wvb, wob);

  gemm_qkv<<<1536, 256, 0, stream>>>(hb, wqb, wkb, wvb, bq, bk, bv,
                                     Qb, Kb, Vth);

  attn_kernel<<<BB * NH * (SS / 128), 256, 0, stream>>>(Qb, Kb, Vth, Cb);

  gemm_out<<<dim3(BS / 128 * (DD / 128)), 256, 0, stream>>>(Cb, wob, bo, out);
}